// Round 1
// baseline (377.189 us; speedup 1.0000x reference)
//
#include <hip/hip_runtime.h>
#include <stdint.h>

// Problem constants (match reference)
#define SLAB 8192    // SL
#define SUNL 16384   // SU
#define DIMX 1024
#define HID1 2048
#define HID2 512
#define KTRIES 8
#define MTOT (SLAB + SUNL)   // 24576

typedef __attribute__((ext_vector_type(8))) short bf16x8;    // 8 bf16 = 4 VGPRs
typedef __attribute__((ext_vector_type(4))) float f32x4;

// fp32 -> bf16 round-to-nearest-even
__device__ __forceinline__ unsigned short f2bf(float f) {
  union { float f; uint32_t u; } c; c.f = f;
  return (unsigned short)((c.u + 0x7fffu + ((c.u >> 16) & 1u)) >> 16);
}

// async global->LDS, 16B per lane; lds dest = wave-uniform base + lane*16
__device__ __forceinline__ void async16(const void* g, void* l) {
  __builtin_amdgcn_global_load_lds(
      (const __attribute__((address_space(1))) unsigned int*)g,
      (__attribute__((address_space(3))) unsigned int*)l,
      16, 0, 0);
}

// ---------------------------------------------------------------------------
// Threefry2x32 (JAX-compatible, 20 rounds)
// ---------------------------------------------------------------------------
struct U2 { uint32_t x, y; };

__device__ __forceinline__ U2 threefry(uint32_t k0, uint32_t k1, uint32_t x0, uint32_t x1) {
  uint32_t ks2 = k0 ^ k1 ^ 0x1BD11BDAu;
  x0 += k0; x1 += k1;
#define TF_R(r) { x0 += x1; x1 = (x1 << (r)) | (x1 >> (32 - (r))); x1 ^= x0; }
  TF_R(13) TF_R(15) TF_R(26) TF_R(6)
  x0 += k1; x1 += ks2 + 1u;
  TF_R(17) TF_R(29) TF_R(16) TF_R(24)
  x0 += ks2; x1 += k0 + 2u;
  TF_R(13) TF_R(15) TF_R(26) TF_R(6)
  x0 += k0; x1 += k1 + 3u;
  TF_R(17) TF_R(29) TF_R(16) TF_R(24)
  x0 += k1; x1 += ks2 + 4u;
  TF_R(13) TF_R(15) TF_R(26) TF_R(6)
  x0 += ks2; x1 += k0 + 5u;
#undef TF_R
  return {x0, x1};
}

// ---------------------------------------------------------------------------
// prep_kernel: one launch for cast(X_l|X_u), transpose-cast W1, W2, and pairs.
// ---------------------------------------------------------------------------
#define XL_BLOCKS (SLAB * DIMX / 4 / 256)           // 8192
#define CAST_BLOCKS (MTOT * DIMX / 4 / 256)         // 24576
#define T1_NBX (HID1 / 32)                          // 64
#define T1_BLOCKS ((HID1 / 32) * (DIMX / 32))       // 2048
#define T2_NBX (HID2 / 32)                          // 16
#define T2_BLOCKS ((HID2 / 32) * (HID1 / 32))       // 1024
#define PAIR_BLOCKS (SUNL / 256)                    // 64
#define PREP_BLOCKS (CAST_BLOCKS + T1_BLOCKS + T2_BLOCKS + PAIR_BLOCKS)

__global__ __launch_bounds__(256) void prep_kernel(
    const float* __restrict__ Xl, const float* __restrict__ Xu,
    const float* __restrict__ W1, const float* __restrict__ W2,
    const float* __restrict__ y_l, const float* __restrict__ y_u,
    unsigned short* __restrict__ X_bf, unsigned short* __restrict__ W1T,
    unsigned short* __restrict__ W2T,
    int* __restrict__ ia, int* __restrict__ ib, float* __restrict__ kv)
{
  __shared__ float t[32][33];
  int b = blockIdx.x;
  int tid = threadIdx.x;

  if (b < CAST_BLOCKS) {
    const float* src; size_t i, doff;
    if (b < XL_BLOCKS) { src = Xl; i = (size_t)b * 256 + tid; doff = 0; }
    else { src = Xu; i = (size_t)(b - XL_BLOCKS) * 256 + tid; doff = (size_t)SLAB * DIMX / 4; }
    float4 v = ((const float4*)src)[i];
    ushort4 o;
    o.x = f2bf(v.x); o.y = f2bf(v.y); o.z = f2bf(v.z); o.w = f2bf(v.w);
    ((ushort4*)X_bf)[doff + i] = o;
  } else if (b < CAST_BLOCKS + T1_BLOCKS + T2_BLOCKS) {
    const float* W; unsigned short* WT; int K, N, bx, by;
    if (b < CAST_BLOCKS + T1_BLOCKS) {
      int tb = b - CAST_BLOCKS;
      W = W1; WT = W1T; K = DIMX; N = HID1; bx = tb % T1_NBX; by = tb / T1_NBX;
    } else {
      int tb = b - CAST_BLOCKS - T1_BLOCKS;
      W = W2; WT = W2T; K = HID1; N = HID2; bx = tb % T2_NBX; by = tb / T2_NBX;
    }
    int k0 = by * 32, n0 = bx * 32;
    int tx = tid & 31, ty = tid >> 5;
#pragma unroll
    for (int i = 0; i < 32; i += 8)
      t[ty + i][tx] = W[(size_t)(k0 + ty + i) * N + n0 + tx];
    __syncthreads();
#pragma unroll
    for (int i = 0; i < 32; i += 8)
      WT[(size_t)(n0 + ty + i) * K + k0 + tx] = f2bf(t[tx][ty + i]);
  } else {
    // pair sampling (verified R1: partitionable threefry, bits1^bits2, &8191)
    int r = (b - CAST_BLOCKS - T1_BLOCKS - T2_BLOCKS) * 256 + tid;
    U2 ka  = threefry(0u, 42u, 0u, 0u);
    U2 kb  = threefry(0u, 42u, 0u, 1u);
    U2 k2a = threefry(ka.x, ka.y, 0u, 1u);
    U2 k2b = threefry(kb.x, kb.y, 0u, 1u);
    int iav[KTRIES], ibv[KTRIES];
#pragma unroll
    for (int c = 0; c < KTRIES; ++c) {
      uint32_t tt = (uint32_t)(r * KTRIES + c);
      U2 oa = threefry(k2a.x, k2a.y, 0u, tt);
      U2 ob = threefry(k2b.x, k2b.y, 0u, tt);
      iav[c] = (int)((oa.x ^ oa.y) & (SLAB - 1));
      ibv[c] = (int)((ob.x ^ ob.y) & (SLAB - 1));
    }
    int a = iav[0], bb2 = ibv[0];
#pragma unroll
    for (int c = 0; c < KTRIES; ++c) {
      if (iav[c] != ibv[c] && y_l[iav[c]] != y_l[ibv[c]]) { a = iav[c]; bb2 = ibv[c]; break; }
    }
    float ya = y_l[a], yb = y_l[bb2];
    ia[r] = a; ib[r] = bb2; kv[r] = (y_u[r] - yb) / (ya - yb);
  }
}

// ---------------------------------------------------------------------------
// bf16 MFMA GEMM, 256x256 tile, BK=64, 8-phase schedule (guide §5 template):
//   - 512 threads = 8 waves (2M x 4N); wave tile 128x64 = 8x4 of 16x16x32.
//   - LDS 128 KB: A,B tiles 256x64 bf16, double-buffered.
//   - Per K-tile: 4 phases {ds_read subtile || 1 half-tile global_load_lds
//     prefetch; barrier; lgkmcnt(0); setprio(1); 16 MFMA; setprio(0); barrier}.
//   - vmcnt(6) ONCE per K-tile (3 half-tiles in flight across barriers);
//     prologue vmcnt(4) after tile0, vmcnt(6) after +3 half-tiles of tile1;
//     epilogue drains via vmcnt(0) at tile NT-2.
//   - XOR swizzle (T2): element (R, c) stored at ushort R*64 + (c ^ ((R&7)<<3)).
//     global_load_lds writes linearly -> pre-swizzle the GLOBAL source chunk
//     (schunk) and apply the same XOR on ds_read (rule #21: both sides).
//     Balance: 8 lanes per 16B slot x 8 slots = conflict-free b128 reads.
//   - Stage->read safety (region granularity = 64-row chunk c0..c3):
//     A c0/c2 consumed ph1, c1/c3 ph3; B rows fully consumed by ph2.
//     ph1 stages A{c1,c3}(t+1)->other buf (read t-1.ph3); ph2 stages
//     A{c0,c2}(t+2)->cur (read ph1); ph3 B{c0,c1}(t+2)->cur (read by ph2);
//     ph4 B{c2,c3}(t+2)->cur (read by ph2). All >=1 barrier separated.
//   - K accumulation order identical to previous kernel (bit-identical out).
// ---------------------------------------------------------------------------
#define GROUP_M 8
#define MFMA_B16(a, b, c) __builtin_amdgcn_mfma_f32_16x16x32_bf16(a, b, c, 0, 0, 0)

template<bool S1, bool S2, int VMC>
__device__ __forceinline__ void ktile256(
    unsigned short* Ac, unsigned short* Bc, unsigned short* Ao,
    const unsigned short* gA, const unsigned short* gB,
    int K, int k1, int k2, int ldst,
    int abase, int bbase, int sw0, int sw1,
    f32x4 (&acc)[8][4])
{
  bf16x8 a0[4][2], a1[4][2], b0[2][2], b1[2][2];

  // ---- phase 1: read A rows [wm,wm+64) + B rows [wn,wn+32); stage A-late(t+1)
#pragma unroll
  for (int i = 0; i < 4; ++i) {
    a0[i][0] = *(const bf16x8*)(Ac + abase + i * 1024 + sw0);
    a0[i][1] = *(const bf16x8*)(Ac + abase + i * 1024 + sw1);
  }
#pragma unroll
  for (int j = 0; j < 2; ++j) {
    b0[j][0] = *(const bf16x8*)(Bc + bbase + j * 1024 + sw0);
    b0[j][1] = *(const bf16x8*)(Bc + bbase + j * 1024 + sw1);
  }
  if (S1) {
    async16(gA + (size_t)64 * K + k1,  Ao + 4096 + ldst);    // A c1
    async16(gA + (size_t)192 * K + k1, Ao + 12288 + ldst);   // A c3
  }
  asm volatile("s_waitcnt lgkmcnt(8)");
  __builtin_amdgcn_s_barrier();
  asm volatile("s_waitcnt lgkmcnt(0)" ::: "memory");
  __builtin_amdgcn_sched_barrier(0);
  __builtin_amdgcn_s_setprio(1);
#pragma unroll
  for (int i = 0; i < 4; ++i)
#pragma unroll
    for (int j = 0; j < 2; ++j) {
      acc[i][j] = MFMA_B16(a0[i][0], b0[j][0], acc[i][j]);
      acc[i][j] = MFMA_B16(a0[i][1], b0[j][1], acc[i][j]);
    }
  __builtin_amdgcn_s_setprio(0);
  __builtin_amdgcn_s_barrier();

  // ---- phase 2: read B rows [wn+32,wn+64); stage A-early(t+2) -> cur buf
#pragma unroll
  for (int j = 0; j < 2; ++j) {
    b1[j][0] = *(const bf16x8*)(Bc + bbase + (j + 2) * 1024 + sw0);
    b1[j][1] = *(const bf16x8*)(Bc + bbase + (j + 2) * 1024 + sw1);
  }
  if (S2) {
    async16(gA + k2,                   Ac + ldst);           // A c0
    async16(gA + (size_t)128 * K + k2, Ac + 8192 + ldst);    // A c2
  }
  __builtin_amdgcn_s_barrier();
  asm volatile("s_waitcnt lgkmcnt(0)" ::: "memory");
  __builtin_amdgcn_sched_barrier(0);
  __builtin_amdgcn_s_setprio(1);
#pragma unroll
  for (int i = 0; i < 4; ++i)
#pragma unroll
    for (int j = 0; j < 2; ++j) {
      acc[i][j + 2] = MFMA_B16(a0[i][0], b1[j][0], acc[i][j + 2]);
      acc[i][j + 2] = MFMA_B16(a0[i][1], b1[j][1], acc[i][j + 2]);
    }
  __builtin_amdgcn_s_setprio(0);
  __builtin_amdgcn_s_barrier();

  // ---- phase 3: read A rows [wm+64,wm+128); stage B-lo(t+2) -> cur buf
#pragma unroll
  for (int i = 0; i < 4; ++i) {
    a1[i][0] = *(const bf16x8*)(Ac + abase + (i + 4) * 1024 + sw0);
    a1[i][1] = *(const bf16x8*)(Ac + abase + (i + 4) * 1024 + sw1);
  }
  if (S2) {
    async16(gB + k2,                  Bc + ldst);            // B c0
    async16(gB + (size_t)64 * K + k2, Bc + 4096 + ldst);     // B c1
  }
  __builtin_amdgcn_s_barrier();
  asm volatile("s_waitcnt lgkmcnt(0)" ::: "memory");
  __builtin_amdgcn_sched_barrier(0);
  __builtin_amdgcn_s_setprio(1);
#pragma unroll
  for (int i = 0; i < 4; ++i)
#pragma unroll
    for (int j = 0; j < 2; ++j) {
      acc[i + 4][j] = MFMA_B16(a1[i][0], b0[j][0], acc[i + 4][j]);
      acc[i + 4][j] = MFMA_B16(a1[i][1], b0[j][1], acc[i + 4][j]);
    }
  __builtin_amdgcn_s_setprio(0);
  __builtin_amdgcn_s_barrier();

  // ---- phase 4: no reads; stage B-hi(t+2); MFMA (1,1); vmcnt; barrier
  if (S2) {
    async16(gB + (size_t)128 * K + k2, Bc + 8192 + ldst);    // B c2
    async16(gB + (size_t)192 * K + k2, Bc + 12288 + ldst);   // B c3
  }
  __builtin_amdgcn_s_barrier();
  asm volatile("s_waitcnt lgkmcnt(0)" ::: "memory");
  __builtin_amdgcn_sched_barrier(0);
  __builtin_amdgcn_s_setprio(1);
#pragma unroll
  for (int i = 0; i < 4; ++i)
#pragma unroll
    for (int j = 0; j < 2; ++j) {
      acc[i + 4][j + 2] = MFMA_B16(a1[i][0], b1[j][0], acc[i + 4][j + 2]);
      acc[i + 4][j + 2] = MFMA_B16(a1[i][1], b1[j][1], acc[i + 4][j + 2]);
    }
  __builtin_amdgcn_s_setprio(0);
  if (VMC == 6)      asm volatile("s_waitcnt vmcnt(6)" ::: "memory");
  else if (VMC == 0) asm volatile("s_waitcnt vmcnt(0)" ::: "memory");
  __builtin_amdgcn_s_barrier();
}

template<int OUT_BF16, int RELU>
__global__ __launch_bounds__(512, 2) void gemm_bt_256(
    const unsigned short* __restrict__ A,   // [M][K] bf16
    const unsigned short* __restrict__ Bt,  // [N][K] bf16
    const float* __restrict__ bias,         // [N] fp32
    void* __restrict__ C0, void* __restrict__ C1, int Msplit,
    int M, int N, int K)
{
  __shared__ unsigned short As[2][16384];   // 2 x 256x64 bf16 = 64 KB
  __shared__ unsigned short Bs[2][16384];   // 64 KB

  const int tid  = threadIdx.x;
  const int wave = tid >> 6;
  const int lane = tid & 63;

  // L2 block swizzle (m-panels of 256 rows), GROUP_M=8 (R4-verified)
  const int nbx = N >> 8;
  const int gsize = nbx * GROUP_M;
  const int grp = blockIdx.x / gsize, within = blockIdx.x % gsize;
  const int m0 = (grp * GROUP_M + (within % GROUP_M)) << 8;
  const int n0 = (within / GROUP_M) << 8;

  const int wm = (wave >> 2) << 7;   // 0 / 128
  const int wn = (wave & 3) << 6;    // 0 / 64 / 128 / 192

  // staging lane geometry: call = 512 lanes x 16B = 64 rows x 128B (one chunk)
  const int srow   = tid >> 3;                  // row within chunk (0..63)
  const int schunk = (tid & 7) ^ (srow & 7);    // pre-swizzled 16B chunk
  const unsigned short* gA = A  + (size_t)(m0 + srow) * K + schunk * 8;
  const unsigned short* gB = Bt + (size_t)(n0 + srow) * K + schunk * 8;
  const int ldst = wave << 9;                   // wave-uniform LDS slice (ushorts)

  // fragment read geometry (16x16x32: lane holds k = q*8..q*8+7 of row fr)
  const int fr = lane & 15, q = lane >> 4;
  const int sw0 = (q << 3) ^ ((fr & 7) << 3);   // ks=0 swizzled col offset
  const int sw1 = sw0 ^ 32;                     // ks=1
  const int abase = (wm + fr) << 6;
  const int bbase = (wn + fr) << 6;

  f32x4 acc[8][4] = {};

  unsigned short* A0p = &As[0][0]; unsigned short* B0p = &Bs[0][0];
  unsigned short* A1p = &As[1][0]; unsigned short* B1p = &Bs[1][0];

  // prologue: tile0 (8 calls) -> vmcnt(4); tile1 {A c0,c2; B c0..c3} -> vmcnt(6)
  async16(gA,                        A0p + ldst);
  async16(gA + (size_t)64 * K,       A0p + 4096 + ldst);
  async16(gA + (size_t)128 * K,      A0p + 8192 + ldst);
  async16(gA + (size_t)192 * K,      A0p + 12288 + ldst);
  async16(gB,                        B0p + ldst);
  async16(gB + (size_t)64 * K,       B0p + 4096 + ldst);
  async16(gB + (size_t)128 * K,      B0p + 8192 + ldst);
  async16(gB + (size_t)192 * K,      B0p + 12288 + ldst);
  asm volatile("s_waitcnt vmcnt(4)" ::: "memory");
  async16(gA + 64,                   A1p + ldst);
  async16(gA + (size_t)128 * K + 64, A1p + 8192 + ldst);
  async16(gB + 64,                   B1p + ldst);
  async16(gB + (size_t)64 * K + 64,  B1p + 4096 + ldst);
  async16(gB + (size_t)128 * K + 64, B1p + 8192 + ldst);
  async16(gB + (size_t)192 * K + 64, B1p + 12288 + ldst);
  asm volatile("s_waitcnt vmcnt(6)" ::: "memory");
  __builtin_amdgcn_s_barrier();

  const int NT = K >> 6;
#pragma unroll 1
  for (int t = 0; t < NT - 2; ++t) {
    const int bb = t & 1;
    ktile256<true, true, 6>(&As[bb][0], &Bs[bb][0], &As[bb ^ 1][0],
                            gA, gB, K, (t + 1) << 6, (t + 2) << 6,
                            ldst, abase, bbase, sw0, sw1, acc);
  }
  {
    const int bb = (NT - 2) & 1;
    ktile256<true, false, 0>(&As[bb][0], &Bs[bb][0], &As[bb ^ 1][0],
                             gA, gB, K, (NT - 1) << 6, 0,
                             ldst, abase, bbase, sw0, sw1, acc);
  }
  {
    const int bb = (NT - 1) & 1;
    ktile256<false, false, -1>(&As[bb][0], &Bs[bb][0], &As[bb ^ 1][0],
                               gA, gB, K, 0, 0,
                               ldst, abase, bbase, sw0, sw1, acc);
  }

  // epilogue: bias + optional relu; per-block output select (tile-aligned)
  // C/D layout: col = lane&15, row = (lane>>4)*4 + reg   [m89/m91 verified]
  void* Cb = (m0 < Msplit) ? C0 : C1;
  const int mbase = (m0 < Msplit) ? m0 : (m0 - Msplit);
  const int crow = mbase + wm + (lane >> 4) * 4;
  const int ccol = n0 + wn + (lane & 15);
#pragma unroll
  for (int j = 0; j < 4; ++j) {
    float bv = bias[ccol + j * 16];
#pragma unroll
    for (int i = 0; i < 8; ++i) {
#pragma unroll
      for (int r = 0; r < 4; ++r) {
        float v = acc[i][j][r] + bv;
        if (RELU) v = fmaxf(v, 0.0f);
        size_t idx = (size_t)(crow + i * 16 + r) * N + ccol + j * 16;
        if (OUT_BF16) ((unsigned short*)Cb)[idx] = f2bf(v);
        else          ((float*)Cb)[idx] = v;
      }
    }
  }
}

// ---------------------------------------------------------------------------
// post_kernel: comb (blocks [0, SUNL/2)) + yhat (blocks [SUNL/2, +SLAB/4))
// ---------------------------------------------------------------------------
#define COMB_BLOCKS (SUNL / 2)              // 8192
#define YHAT_BLOCKS (SLAB / 4)              // 2048
#define POST_BLOCKS (COMB_BLOCKS + YHAT_BLOCKS)

__global__ __launch_bounds__(256) void post_kernel(
    const float* __restrict__ feat_l, const float* __restrict__ W3,
    const float* __restrict__ b3, const int* __restrict__ ia,
    const int* __restrict__ ib, const float* __restrict__ kv,
    float* __restrict__ out_comb, float* __restrict__ out_yhat)
{
  int b = blockIdx.x;
  if (b < COMB_BLOCKS) {
    int row = b * 2 + (threadIdx.x >> 7);
    int c = (threadIdx.x & 127) << 2;
    float k = kv[row];
    float km1 = 1.0f - k;
    float4 fa = *(const float4*)(feat_l + (size_t)ia[row] * HID2 + c);
    float4 fb = *(const float4*)(feat_l + (size_t)ib[row] * HID2 + c);
    float4 o;
    o.x = k * fa.x + km1 * fb.x;
    o.y = k * fa.y + km1 * fb.y;
    o.z = k * fa.z + km1 * fb.z;
    o.w = k * fa.w + km1 * fb.w;
    *(float4*)(out_comb + (size_t)row * HID2 + c) = o;
  } else {
    int wave = threadIdx.x >> 6;
    int lane = threadIdx.x & 63;
    int row = (b - COMB_BLOCKS) * 4 + wave;
    const float* f = feat_l + (size_t)row * HID2;
    float s = 0.f;
#pragma unroll
    for (int j = 0; j < HID2 / 64; ++j) s = fmaf(f[lane + j * 64], W3[lane + j * 64], s);
#pragma unroll
    for (int off = 32; off; off >>= 1) s += __shfl_down(s, off);
    if (lane == 0) out_yhat[row] = s + b3[0];
  }
}

// ---------------------------------------------------------------------------
extern "C" void kernel_launch(void* const* d_in, const int* in_sizes, int n_in,
                              void* d_out, int out_size, void* d_ws, size_t ws_size,
                              hipStream_t stream)
{
  const float* X_l = (const float*)d_in[0];
  const float* y_l = (const float*)d_in[1];
  const float* X_u = (const float*)d_in[2];
  const float* y_u = (const float*)d_in[3];
  const float* W1  = (const float*)d_in[4];
  const float* b1  = (const float*)d_in[5];
  const float* W2  = (const float*)d_in[6];
  const float* b2  = (const float*)d_in[7];
  const float* W3  = (const float*)d_in[8];
  const float* b3  = (const float*)d_in[9];

  float* out_featu = (float*)d_out;
  float* out_comb  = out_featu + (size_t)SUNL * HID2;
  float* out_yhat  = out_comb + (size_t)SUNL * HID2;

  // Workspace (~174 MB): X_bf = [Xl|Xu] contig, H_bf = [Hl|Hu] contig
  unsigned short* X_bf  = (unsigned short*)d_ws;                 // [24576][1024]
  unsigned short* W1T   = X_bf + (size_t)MTOT * DIMX;
  unsigned short* W2T   = W1T + (size_t)HID1 * DIMX;
  unsigned short* H_bf  = W2T + (size_t)HID2 * HID1;             // [24576][2048]
  float* feat_l = (float*)(H_bf + (size_t)MTOT * HID1);
  int*   ai = (int*)(feat_l + (size_t)SLAB * HID2);
  int*   bi = ai + SUNL;
  float* kv = (float*)(bi + SUNL);

  prep_kernel<<<dim3(PREP_BLOCKS), dim3(256), 0, stream>>>(
      X_l, X_u, W1, W2, y_l, y_u, X_bf, W1T, W2T, ai, bi, kv);

  // layer 1 (merged l+u): H = relu(X @ W1 + b1) -> bf16  [768 blocks x 512]
  gemm_bt_256<1, 1><<<dim3((HID1 / 256) * (MTOT / 256)), dim3(512), 0, stream>>>(
      X_bf, W1T, b1, H_bf, H_bf, MTOT /*no split*/, MTOT, HID1, DIMX);

  // layer 2 (merged l+u): feat = relu(H @ W2 + b2) -> fp32, split dest [192 blocks]
  gemm_bt_256<0, 1><<<dim3((HID2 / 256) * (MTOT / 256)), dim3(512), 0, stream>>>(
      H_bf, W2T, b2, feat_l, out_featu, SLAB, MTOT, HID2, HID1);

  post_kernel<<<dim3(POST_BLOCKS), dim3(256), 0, stream>>>(
      feat_l, W3, b3, ai, bi, kv, out_comb, out_yhat);
}

// Round 2
// 344.851 us; speedup vs baseline: 1.0938x; 1.0938x over previous
//
#include <hip/hip_runtime.h>
#include <stdint.h>

// Problem constants (match reference)
#define SLAB 8192    // SL
#define SUNL 16384   // SU
#define DIMX 1024
#define HID1 2048
#define HID2 512
#define KTRIES 8
#define MTOT (SLAB + SUNL)   // 24576

typedef __attribute__((ext_vector_type(8))) short bf16x8;    // 8 bf16 = 4 VGPRs
typedef __attribute__((ext_vector_type(4))) float f32x4;

// fp32 -> bf16 round-to-nearest-even
__device__ __forceinline__ unsigned short f2bf(float f) {
  union { float f; uint32_t u; } c; c.f = f;
  return (unsigned short)((c.u + 0x7fffu + ((c.u >> 16) & 1u)) >> 16);
}

// async global->LDS, 16B per lane; lds dest = wave-uniform base + lane*16
__device__ __forceinline__ void async16(const void* g, void* l) {
  __builtin_amdgcn_global_load_lds(
      (const __attribute__((address_space(1))) unsigned int*)g,
      (__attribute__((address_space(3))) unsigned int*)l,
      16, 0, 0);
}

// ---------------------------------------------------------------------------
// Threefry2x32 (JAX-compatible, 20 rounds)
// ---------------------------------------------------------------------------
struct U2 { uint32_t x, y; };

__device__ __forceinline__ U2 threefry(uint32_t k0, uint32_t k1, uint32_t x0, uint32_t x1) {
  uint32_t ks2 = k0 ^ k1 ^ 0x1BD11BDAu;
  x0 += k0; x1 += k1;
#define TF_R(r) { x0 += x1; x1 = (x1 << (r)) | (x1 >> (32 - (r))); x1 ^= x0; }
  TF_R(13) TF_R(15) TF_R(26) TF_R(6)
  x0 += k1; x1 += ks2 + 1u;
  TF_R(17) TF_R(29) TF_R(16) TF_R(24)
  x0 += ks2; x1 += k0 + 2u;
  TF_R(13) TF_R(15) TF_R(26) TF_R(6)
  x0 += k0; x1 += k1 + 3u;
  TF_R(17) TF_R(29) TF_R(16) TF_R(24)
  x0 += k1; x1 += ks2 + 4u;
  TF_R(13) TF_R(15) TF_R(26) TF_R(6)
  x0 += ks2; x1 += k0 + 5u;
#undef TF_R
  return {x0, x1};
}

// ---------------------------------------------------------------------------
// prep_kernel: one launch for cast(X_l|X_u), transpose-cast W1, W2, and pairs.
// ---------------------------------------------------------------------------
#define XL_BLOCKS (SLAB * DIMX / 4 / 256)           // 8192
#define CAST_BLOCKS (MTOT * DIMX / 4 / 256)         // 24576
#define T1_NBX (HID1 / 32)                          // 64
#define T1_BLOCKS ((HID1 / 32) * (DIMX / 32))       // 2048
#define T2_NBX (HID2 / 32)                          // 16
#define T2_BLOCKS ((HID2 / 32) * (HID1 / 32))       // 1024
#define PAIR_BLOCKS (SUNL / 256)                    // 64
#define PREP_BLOCKS (CAST_BLOCKS + T1_BLOCKS + T2_BLOCKS + PAIR_BLOCKS)

__global__ __launch_bounds__(256) void prep_kernel(
    const float* __restrict__ Xl, const float* __restrict__ Xu,
    const float* __restrict__ W1, const float* __restrict__ W2,
    const float* __restrict__ y_l, const float* __restrict__ y_u,
    unsigned short* __restrict__ X_bf, unsigned short* __restrict__ W1T,
    unsigned short* __restrict__ W2T,
    int* __restrict__ ia, int* __restrict__ ib, float* __restrict__ kv)
{
  __shared__ float t[32][33];
  int b = blockIdx.x;
  int tid = threadIdx.x;

  if (b < CAST_BLOCKS) {
    const float* src; size_t i, doff;
    if (b < XL_BLOCKS) { src = Xl; i = (size_t)b * 256 + tid; doff = 0; }
    else { src = Xu; i = (size_t)(b - XL_BLOCKS) * 256 + tid; doff = (size_t)SLAB * DIMX / 4; }
    float4 v = ((const float4*)src)[i];
    ushort4 o;
    o.x = f2bf(v.x); o.y = f2bf(v.y); o.z = f2bf(v.z); o.w = f2bf(v.w);
    ((ushort4*)X_bf)[doff + i] = o;
  } else if (b < CAST_BLOCKS + T1_BLOCKS + T2_BLOCKS) {
    const float* W; unsigned short* WT; int K, N, bx, by;
    if (b < CAST_BLOCKS + T1_BLOCKS) {
      int tb = b - CAST_BLOCKS;
      W = W1; WT = W1T; K = DIMX; N = HID1; bx = tb % T1_NBX; by = tb / T1_NBX;
    } else {
      int tb = b - CAST_BLOCKS - T1_BLOCKS;
      W = W2; WT = W2T; K = HID1; N = HID2; bx = tb % T2_NBX; by = tb / T2_NBX;
    }
    int k0 = by * 32, n0 = bx * 32;
    int tx = tid & 31, ty = tid >> 5;
#pragma unroll
    for (int i = 0; i < 32; i += 8)
      t[ty + i][tx] = W[(size_t)(k0 + ty + i) * N + n0 + tx];
    __syncthreads();
#pragma unroll
    for (int i = 0; i < 32; i += 8)
      WT[(size_t)(n0 + ty + i) * K + k0 + tx] = f2bf(t[tx][ty + i]);
  } else {
    // pair sampling (verified R1: partitionable threefry, bits1^bits2, &8191)
    int r = (b - CAST_BLOCKS - T1_BLOCKS - T2_BLOCKS) * 256 + tid;
    U2 ka  = threefry(0u, 42u, 0u, 0u);
    U2 kb  = threefry(0u, 42u, 0u, 1u);
    U2 k2a = threefry(ka.x, ka.y, 0u, 1u);
    U2 k2b = threefry(kb.x, kb.y, 0u, 1u);
    int iav[KTRIES], ibv[KTRIES];
#pragma unroll
    for (int c = 0; c < KTRIES; ++c) {
      uint32_t tt = (uint32_t)(r * KTRIES + c);
      U2 oa = threefry(k2a.x, k2a.y, 0u, tt);
      U2 ob = threefry(k2b.x, k2b.y, 0u, tt);
      iav[c] = (int)((oa.x ^ oa.y) & (SLAB - 1));
      ibv[c] = (int)((ob.x ^ ob.y) & (SLAB - 1));
    }
    int a = iav[0], bb2 = ibv[0];
#pragma unroll
    for (int c = 0; c < KTRIES; ++c) {
      if (iav[c] != ibv[c] && y_l[iav[c]] != y_l[ibv[c]]) { a = iav[c]; bb2 = ibv[c]; break; }
    }
    float ya = y_l[a], yb = y_l[bb2];
    ia[r] = a; ib[r] = bb2; kv[r] = (y_u[r] - yb) / (ya - yb);
  }
}

// ---------------------------------------------------------------------------
// bf16 MFMA GEMM, 256x256 tile, BK=64, counted-wait schedule (T3+T4 fixed):
//   - 512 threads = 8 waves (2M x 4N); wave tile 128x64 = 8x4 of 16x16x32.
//   - LDS 128 KB: A,B tiles 256x64 bf16, double-buffered.
//   - Per K-tile: ALL 24 ds_read_b128 burst-issued at tile start in pinned
//     order (a0:8, b0:4 | b1:4 | a1:8 via sched_barrier(0)); quadrant MFMAs
//     gated by counted IN-ORDER lgkmcnt waits: q1 lgkm(12), q2 lgkm(8),
//     q3 lgkm(0), q4 none. LDS drain overlaps MFMA (R1's per-phase
//     lgkmcnt(0) serialized drain vs MFMA -> 27% MfmaUtil).
//   - 4 barriers/tile (was 8). Stage hazards: A c0/c2 staged after bar1
//     (all a0 reads done via lgkm(12)+bar); B c0/c1 after bar2 (b0,b1 done
//     via lgkm(8)+bar); B c2/c3 after bar3; no stage touches cur A c1/c3;
//     S1 (A c1,c3 of t+1 -> other buf) regions fully read last tile.
//   - vmcnt(6) once per tile after q4: drains t-1's 6 staged + t's S1 2
//     = tile t+1 fully resident; 6 left = t's S2 (t+2 partial). Invariant
//     holds from prologue (8 tile0 + 6 tile1-partial, vmcnt(6)).
//   - XOR swizzle (T2): element (R,c16) at ushort R*64 + 8*(c16 ^ (R&7));
//     global source pre-swizzled (schunk), same XOR on ds_read (rule #21).
//     0 bank conflicts measured (R1).
//   - K accumulation order identical to R0/R1 (bit-identical output).
// ---------------------------------------------------------------------------
#define GROUP_M 8
#define MFMA_B16(a, b, c) __builtin_amdgcn_mfma_f32_16x16x32_bf16(a, b, c, 0, 0, 0)

template<bool S1, bool S2, int VMC>
__device__ __forceinline__ void ktile256(
    unsigned short* Ac, unsigned short* Bc, unsigned short* Ao,
    const unsigned short* gA, const unsigned short* gB,
    int K, int k1, int k2, int ldst,
    int abase, int bbase, int sw0, int sw1,
    f32x4 (&acc)[8][4])
{
  bf16x8 a0[4][2], a1[4][2], b0[2][2], b1[2][2];

  // S1 first: start HBM fetch of tile t+1's A c1,c3 ASAP (other buffer;
  // those regions were fully read during tile t-1, barrier-separated).
  if (S1) {
    async16(gA + (size_t)64 * K + k1,  Ao + 4096 + ldst);    // A c1 (t+1)
    async16(gA + (size_t)192 * K + k1, Ao + 12288 + ldst);   // A c3 (t+1)
  }

  // ---- burst: 24 ds_reads, group order pinned (counted waits depend on it)
#pragma unroll
  for (int i = 0; i < 4; ++i) {
    a0[i][0] = *(const bf16x8*)(Ac + abase + i * 1024 + sw0);
    a0[i][1] = *(const bf16x8*)(Ac + abase + i * 1024 + sw1);
  }
#pragma unroll
  for (int j = 0; j < 2; ++j) {
    b0[j][0] = *(const bf16x8*)(Bc + bbase + j * 1024 + sw0);
    b0[j][1] = *(const bf16x8*)(Bc + bbase + j * 1024 + sw1);
  }
  __builtin_amdgcn_sched_barrier(0);
#pragma unroll
  for (int j = 0; j < 2; ++j) {
    b1[j][0] = *(const bf16x8*)(Bc + bbase + (j + 2) * 1024 + sw0);
    b1[j][1] = *(const bf16x8*)(Bc + bbase + (j + 2) * 1024 + sw1);
  }
  __builtin_amdgcn_sched_barrier(0);
#pragma unroll
  for (int i = 0; i < 4; ++i) {
    a1[i][0] = *(const bf16x8*)(Ac + abase + (i + 4) * 1024 + sw0);
    a1[i][1] = *(const bf16x8*)(Ac + abase + (i + 4) * 1024 + sw1);
  }
  __builtin_amdgcn_sched_barrier(0);

  // ---- q1: a0 x b0 -> acc[0..3][0..1]   (needs first 12 reads)
  asm volatile("s_waitcnt lgkmcnt(12)" ::: "memory");
  __builtin_amdgcn_sched_barrier(0);
  __builtin_amdgcn_s_setprio(1);
#pragma unroll
  for (int i = 0; i < 4; ++i)
#pragma unroll
    for (int j = 0; j < 2; ++j) {
      acc[i][j] = MFMA_B16(a0[i][0], b0[j][0], acc[i][j]);
      acc[i][j] = MFMA_B16(a0[i][1], b0[j][1], acc[i][j]);
    }
  __builtin_amdgcn_s_setprio(0);
  __builtin_amdgcn_s_barrier();

  // ---- q2: a0 x b1 -> acc[0..3][2..3]   (needs first 16 reads)
  if (S2) {
    async16(gA + k2,                   Ac + ldst);           // A c0 (t+2)
    async16(gA + (size_t)128 * K + k2, Ac + 8192 + ldst);    // A c2 (t+2)
  }
  asm volatile("s_waitcnt lgkmcnt(8)" ::: "memory");
  __builtin_amdgcn_sched_barrier(0);
  __builtin_amdgcn_s_setprio(1);
#pragma unroll
  for (int i = 0; i < 4; ++i)
#pragma unroll
    for (int j = 0; j < 2; ++j) {
      acc[i][j + 2] = MFMA_B16(a0[i][0], b1[j][0], acc[i][j + 2]);
      acc[i][j + 2] = MFMA_B16(a0[i][1], b1[j][1], acc[i][j + 2]);
    }
  __builtin_amdgcn_s_setprio(0);
  __builtin_amdgcn_s_barrier();

  // ---- q3: a1 x b0 -> acc[4..7][0..1]   (needs all 24 reads)
  if (S2) {
    async16(gB + k2,                  Bc + ldst);            // B c0 (t+2)
    async16(gB + (size_t)64 * K + k2, Bc + 4096 + ldst);     // B c1 (t+2)
  }
  asm volatile("s_waitcnt lgkmcnt(0)" ::: "memory");
  __builtin_amdgcn_sched_barrier(0);
  __builtin_amdgcn_s_setprio(1);
#pragma unroll
  for (int i = 0; i < 4; ++i)
#pragma unroll
    for (int j = 0; j < 2; ++j) {
      acc[i + 4][j] = MFMA_B16(a1[i][0], b0[j][0], acc[i + 4][j]);
      acc[i + 4][j] = MFMA_B16(a1[i][1], b0[j][1], acc[i + 4][j]);
    }
  __builtin_amdgcn_s_setprio(0);
  __builtin_amdgcn_s_barrier();

  // ---- q4: a1 x b1 -> acc[4..7][2..3]   (no new reads); vmcnt; barrier
  if (S2) {
    async16(gB + (size_t)128 * K + k2, Bc + 8192 + ldst);    // B c2 (t+2)
    async16(gB + (size_t)192 * K + k2, Bc + 12288 + ldst);   // B c3 (t+2)
  }
  __builtin_amdgcn_s_setprio(1);
#pragma unroll
  for (int i = 0; i < 4; ++i)
#pragma unroll
    for (int j = 0; j < 2; ++j) {
      acc[i + 4][j + 2] = MFMA_B16(a1[i][0], b1[j][0], acc[i + 4][j + 2]);
      acc[i + 4][j + 2] = MFMA_B16(a1[i][1], b1[j][1], acc[i + 4][j + 2]);
    }
  __builtin_amdgcn_s_setprio(0);
  if (VMC == 6)      asm volatile("s_waitcnt vmcnt(6)" ::: "memory");
  else if (VMC == 0) asm volatile("s_waitcnt vmcnt(0)" ::: "memory");
  __builtin_amdgcn_s_barrier();
}

template<int OUT_BF16, int RELU>
__global__ __launch_bounds__(512, 2) void gemm_bt_256(
    const unsigned short* __restrict__ A,   // [M][K] bf16
    const unsigned short* __restrict__ Bt,  // [N][K] bf16
    const float* __restrict__ bias,         // [N] fp32
    void* __restrict__ C0, void* __restrict__ C1, int Msplit,
    int M, int N, int K)
{
  __shared__ unsigned short As[2][16384];   // 2 x 256x64 bf16 = 64 KB
  __shared__ unsigned short Bs[2][16384];   // 64 KB

  const int tid  = threadIdx.x;
  const int wave = tid >> 6;
  const int lane = tid & 63;

  // L2 block swizzle (m-panels of 256 rows), GROUP_M=8 (R4-verified)
  const int nbx = N >> 8;
  const int gsize = nbx * GROUP_M;
  const int grp = blockIdx.x / gsize, within = blockIdx.x % gsize;
  const int m0 = (grp * GROUP_M + (within % GROUP_M)) << 8;
  const int n0 = (within / GROUP_M) << 8;

  const int wm = (wave >> 2) << 7;   // 0 / 128
  const int wn = (wave & 3) << 6;    // 0 / 64 / 128 / 192

  // staging lane geometry: call = 512 lanes x 16B = 64 rows x 128B (one chunk)
  const int srow   = tid >> 3;                  // row within chunk (0..63)
  const int schunk = (tid & 7) ^ (srow & 7);    // pre-swizzled 16B chunk
  const unsigned short* gA = A  + (size_t)(m0 + srow) * K + schunk * 8;
  const unsigned short* gB = Bt + (size_t)(n0 + srow) * K + schunk * 8;
  const int ldst = wave << 9;                   // wave-uniform LDS slice (ushorts)

  // fragment read geometry (16x16x32: lane holds k = q*8..q*8+7 of row fr)
  const int fr = lane & 15, q = lane >> 4;
  const int sw0 = (q << 3) ^ ((fr & 7) << 3);   // ks=0 swizzled col offset
  const int sw1 = sw0 ^ 32;                     // ks=1
  const int abase = (wm + fr) << 6;
  const int bbase = (wn + fr) << 6;

  f32x4 acc[8][4] = {};

  unsigned short* A0p = &As[0][0]; unsigned short* B0p = &Bs[0][0];
  unsigned short* A1p = &As[1][0]; unsigned short* B1p = &Bs[1][0];

  // prologue: tile0 full (8 calls) + tile1 partial {A c0,c2; B c0..c3};
  // vmcnt(6) -> tile0 resident, 6 outstanding = tile1 partial (invariant).
  async16(gA,                        A0p + ldst);
  async16(gA + (size_t)64 * K,       A0p + 4096 + ldst);
  async16(gA + (size_t)128 * K,      A0p + 8192 + ldst);
  async16(gA + (size_t)192 * K,      A0p + 12288 + ldst);
  async16(gB,                        B0p + ldst);
  async16(gB + (size_t)64 * K,       B0p + 4096 + ldst);
  async16(gB + (size_t)128 * K,      B0p + 8192 + ldst);
  async16(gB + (size_t)192 * K,      B0p + 12288 + ldst);
  async16(gA + 64,                   A1p + ldst);
  async16(gA + (size_t)128 * K + 64, A1p + 8192 + ldst);
  async16(gB + 64,                   B1p + ldst);
  async16(gB + (size_t)64 * K + 64,  B1p + 4096 + ldst);
  async16(gB + (size_t)128 * K + 64, B1p + 8192 + ldst);
  async16(gB + (size_t)192 * K + 64, B1p + 12288 + ldst);
  asm volatile("s_waitcnt vmcnt(6)" ::: "memory");
  __builtin_amdgcn_s_barrier();

  const int NT = K >> 6;
#pragma unroll 1
  for (int t = 0; t < NT - 2; ++t) {
    const int bb = t & 1;
    ktile256<true, true, 6>(&As[bb][0], &Bs[bb][0], &As[bb ^ 1][0],
                            gA, gB, K, (t + 1) << 6, (t + 2) << 6,
                            ldst, abase, bbase, sw0, sw1, acc);
  }
  {
    const int bb = (NT - 2) & 1;
    ktile256<true, false, 0>(&As[bb][0], &Bs[bb][0], &As[bb ^ 1][0],
                             gA, gB, K, (NT - 1) << 6, 0,
                             ldst, abase, bbase, sw0, sw1, acc);
  }
  {
    const int bb = (NT - 1) & 1;
    ktile256<false, false, -1>(&As[bb][0], &Bs[bb][0], &As[bb ^ 1][0],
                               gA, gB, K, 0, 0,
                               ldst, abase, bbase, sw0, sw1, acc);
  }

  // epilogue: bias + optional relu; per-block output select (tile-aligned)
  // C/D layout: col = lane&15, row = (lane>>4)*4 + reg   [m89/m91 verified]
  // j INNERMOST: each 128B output line completed in 4 consecutive stores
  // (R1 j-outer held 128 dirty-partial lines/wave across the epilogue ->
  //  L2 evictions -> WRITE_SIZE 201 MB for a 100 MB output).
  void* Cb = (m0 < Msplit) ? C0 : C1;
  const int mbase = (m0 < Msplit) ? m0 : (m0 - Msplit);
  const int crow = mbase + wm + (lane >> 4) * 4;
  const int ccol = n0 + wn + (lane & 15);
  float bv[4];
#pragma unroll
  for (int j = 0; j < 4; ++j) bv[j] = bias[ccol + j * 16];
#pragma unroll
  for (int i = 0; i < 8; ++i) {
#pragma unroll
    for (int r = 0; r < 4; ++r) {
      size_t base = (size_t)(crow + i * 16 + r) * N + ccol;
#pragma unroll
      for (int j = 0; j < 4; ++j) {
        float v = acc[i][j][r] + bv[j];
        if (RELU) v = fmaxf(v, 0.0f);
        if (OUT_BF16) ((unsigned short*)Cb)[base + j * 16] = f2bf(v);
        else          ((float*)Cb)[base + j * 16] = v;
      }
    }
  }
}

// ---------------------------------------------------------------------------
// post_kernel: comb (blocks [0, SUNL/2)) + yhat (blocks [SUNL/2, +SLAB/4))
// ---------------------------------------------------------------------------
#define COMB_BLOCKS (SUNL / 2)              // 8192
#define YHAT_BLOCKS (SLAB / 4)              // 2048
#define POST_BLOCKS (COMB_BLOCKS + YHAT_BLOCKS)

__global__ __launch_bounds__(256) void post_kernel(
    const float* __restrict__ feat_l, const float* __restrict__ W3,
    const float* __restrict__ b3, const int* __restrict__ ia,
    const int* __restrict__ ib, const float* __restrict__ kv,
    float* __restrict__ out_comb, float* __restrict__ out_yhat)
{
  int b = blockIdx.x;
  if (b < COMB_BLOCKS) {
    int row = b * 2 + (threadIdx.x >> 7);
    int c = (threadIdx.x & 127) << 2;
    float k = kv[row];
    float km1 = 1.0f - k;
    float4 fa = *(const float4*)(feat_l + (size_t)ia[row] * HID2 + c);
    float4 fb = *(const float4*)(feat_l + (size_t)ib[row] * HID2 + c);
    float4 o;
    o.x = k * fa.x + km1 * fb.x;
    o.y = k * fa.y + km1 * fb.y;
    o.z = k * fa.z + km1 * fb.z;
    o.w = k * fa.w + km1 * fb.w;
    *(float4*)(out_comb + (size_t)row * HID2 + c) = o;
  } else {
    int wave = threadIdx.x >> 6;
    int lane = threadIdx.x & 63;
    int row = (b - COMB_BLOCKS) * 4 + wave;
    const float* f = feat_l + (size_t)row * HID2;
    float s = 0.f;
#pragma unroll
    for (int j = 0; j < HID2 / 64; ++j) s = fmaf(f[lane + j * 64], W3[lane + j * 64], s);
#pragma unroll
    for (int off = 32; off; off >>= 1) s += __shfl_down(s, off);
    if (lane == 0) out_yhat[row] = s + b3[0];
  }
}

// ---------------------------------------------------------------------------
extern "C" void kernel_launch(void* const* d_in, const int* in_sizes, int n_in,
                              void* d_out, int out_size, void* d_ws, size_t ws_size,
                              hipStream_t stream)
{
  const float* X_l = (const float*)d_in[0];
  const float* y_l = (const float*)d_in[1];
  const float* X_u = (const float*)d_in[2];
  const float* y_u = (const float*)d_in[3];
  const float* W1  = (const float*)d_in[4];
  const float* b1  = (const float*)d_in[5];
  const float* W2  = (const float*)d_in[6];
  const float* b2  = (const float*)d_in[7];
  const float* W3  = (const float*)d_in[8];
  const float* b3  = (const float*)d_in[9];

  float* out_featu = (float*)d_out;
  float* out_comb  = out_featu + (size_t)SUNL * HID2;
  float* out_yhat  = out_comb + (size_t)SUNL * HID2;

  // Workspace (~174 MB): X_bf = [Xl|Xu] contig, H_bf = [Hl|Hu] contig
  unsigned short* X_bf  = (unsigned short*)d_ws;                 // [24576][1024]
  unsigned short* W1T   = X_bf + (size_t)MTOT * DIMX;
  unsigned short* W2T   = W1T + (size_t)HID1 * DIMX;
  unsigned short* H_bf  = W2T + (size_t)HID2 * HID1;             // [24576][2048]
  float* feat_l = (float*)(H_bf + (size_t)MTOT * HID1);
  int*   ai = (int*)(feat_l + (size_t)SLAB * HID2);
  int*   bi = ai + SUNL;
  float* kv = (float*)(bi + SUNL);

  prep_kernel<<<dim3(PREP_BLOCKS), dim3(256), 0, stream>>>(
      X_l, X_u, W1, W2, y_l, y_u, X_bf, W1T, W2T, ai, bi, kv);

  // layer 1 (merged l+u): H = relu(X @ W1 + b1) -> bf16  [768 blocks x 512]
  gemm_bt_256<1, 1><<<dim3((HID1 / 256) * (MTOT / 256)), dim3(512), 0, stream>>>(
      X_bf, W1T, b1, H_bf, H_bf, MTOT /*no split*/, MTOT, HID1, DIMX);

  // layer 2 (merged l+u): feat = relu(H @ W2 + b2) -> fp32, split dest [192 blocks]
  gemm_bt_256<0, 1><<<dim3((HID2 / 256) * (MTOT / 256)), dim3(512), 0, stream>>>(
      H_bf, W2T, b2, feat_l, out_featu, SLAB, MTOT, HID2, HID1);

  post_kernel<<<dim3(POST_BLOCKS), dim3(256), 0, stream>>>(
      feat_l, W3, b3, ai, bi, kv, out_comb, out_yhat);
}